// Round 3
// baseline (237.328 us; speedup 1.0000x reference)
//
#include <hip/hip_runtime.h>

// EMA over time: y_t = 0.1*y_{t-1} + 0.9*x_t, x: [B=16, T=4000, C=512] fp32.
// Chunked-scan with truncated warmup: 0.1^8 ~ 1e-8 (threshold 7.8e-3).
// Each thread owns one (b, c4) column for L=16 timesteps, warming up over
// the previous W=8.
//
// R6: R5's counters showed VGPR_Count=36 — the compiler SANK the intended
// 24-deep load batch back to the uses (both R3 and R5), leaving a narrow
// load->wait->FMA->store chain per wave and a ~2.5 TB/s service-rate wall
// (all pipes idle: VALU 2.6%, HBM 31%, occ 28%). Fixes:
//   1. sched_barrier(0) after the load block: forces all 24 loads issued
//      back-to-back before any consumption (real MLP, one vmcnt drain).
//   2. Phase-separated stores: compute all 16 outputs into registers, then
//      store them in one tight block (second sched_barrier) — each wave is
//      a pure read burst then a pure write burst, instead of interleaving
//      loads and stores at DRAM turnaround granularity.
//   3. L=16 so w[8]+m[16]+o[16] (overlapping lifetimes) fits the 128-VGPR
//      cap of __launch_bounds__(256,4); grid 2000 blocks for occupancy.
// Plain stores (nt was neutral-to-negative in R5).

constexpr int B_ = 16;
constexpr int T_ = 4000;
constexpr int C_ = 512;
constexpr int L_ = 16;            // output timesteps per thread
constexpr int W_ = 8;             // lookback warmup (0.1^8 ~ 1e-8)
constexpr int NC4_ = C_ / 4;      // 128 float4 columns per row
constexpr int NCHUNK_ = T_ / L_;  // 250

__global__ __launch_bounds__(256, 4) void ema_chunk_scan(const float* __restrict__ x,
                                                         float* __restrict__ y) {
    int g = blockIdx.x * blockDim.x + threadIdx.x;
    int c4 = g & (NC4_ - 1);          // lane-major over channels -> coalesced
    int bt = g >> 7;                  // / NC4_
    int b  = bt & (B_ - 1);
    int chunk = bt >> 4;              // / B_  (wave-uniform)

    int t0 = chunk * L_;
    int tw = (chunk > 0) ? (t0 - W_) : 0;

    const float4* base = (const float4*)(x + (size_t)b * T_ * C_) + c4;
    float4*       q    = (float4*)(y + ((size_t)b * T_ + t0) * C_) + c4;

    // ---- phase 1: issue ALL 24 loads, fenced so the scheduler cannot
    // sink them into the compute phase ----
    float4 w[W_];
    #pragma unroll
    for (int i = 0; i < W_; ++i) w[i] = base[(size_t)(tw + i) * NC4_];
    float4 m[L_];
    #pragma unroll
    for (int i = 0; i < L_; ++i) m[i] = base[(size_t)(t0 + i) * NC4_];
    __builtin_amdgcn_sched_barrier(0);

    const float a = 0.9f, om = 0.1f;
    float4 acc = make_float4(0.f, 0.f, 0.f, 0.f);

    // ---- phase 2: warmup chain (no stores) ----
    #pragma unroll
    for (int i = 0; i < W_; ++i) {
        acc.x = om * acc.x + a * w[i].x;
        acc.y = om * acc.y + a * w[i].y;
        acc.z = om * acc.z + a * w[i].z;
        acc.w = om * acc.w + a * w[i].w;
    }
    // chunk 0: no history — zero the warmup state (wave-uniform select).
    float sel = (chunk > 0) ? 1.f : 0.f;
    acc.x *= sel; acc.y *= sel; acc.z *= sel; acc.w *= sel;

    // main chain into registers (no stores yet)
    float4 o[L_];
    #pragma unroll
    for (int i = 0; i < L_; ++i) {
        acc.x = om * acc.x + a * m[i].x;
        acc.y = om * acc.y + a * m[i].y;
        acc.z = om * acc.z + a * m[i].z;
        acc.w = om * acc.w + a * m[i].w;
        o[i] = acc;
    }
    __builtin_amdgcn_sched_barrier(0);

    // ---- phase 3: pure store burst ----
    #pragma unroll
    for (int i = 0; i < L_; ++i) {
        q[(size_t)i * NC4_] = o[i];
    }
}

extern "C" void kernel_launch(void* const* d_in, const int* in_sizes, int n_in,
                              void* d_out, int out_size, void* d_ws, size_t ws_size,
                              hipStream_t stream) {
    const float* x = (const float*)d_in[0];
    float* y = (float*)d_out;
    int total_threads = B_ * NC4_ * NCHUNK_;   // 512,000
    int block = 256;
    int grid = total_threads / block;          // 2000
    ema_chunk_scan<<<grid, block, 0, stream>>>(x, y);
}

// Round 4
// 229.918 us; speedup vs baseline: 1.0322x; 1.0322x over previous
//
#include <hip/hip_runtime.h>

// EMA over time: y_t = 0.1*y_{t-1} + 0.9*x_t, x: [B=16, T=4000, C=512] fp32.
// Chunked-scan with truncated warmup: 0.1^8 ~ 1e-8 (threshold 7.8e-3).
// Each thread owns one (b, c4) column for L=16 timesteps, warming up over
// the previous W=8.
//
// R7: ordering experiment. R3/R5/R6 (three different shapes) all sat at
// ~83 us / 2.5 TB/s with every pipe idle (VALU 3%, occ 28-44%, latency
// math says MLP is sufficient). Common untested variable: b-major work
// order — consecutive blocks walk consecutive BATCHES (8 MB apart), so
// ~880 resident blocks present ~3500 scattered 48 KB windows to DRAM
// (row-thrash => ~40% efficiency), and chunk k's warmup re-reads of chunk
// k-1's tail rows land on a DIFFERENT XCD's L2 (b-major + round-robin
// dispatch). This round changes ONLY the ordering:
//   - chunk-major decode: block covers 2 consecutive chunks of ONE b.
//   - bijective XCD swizzle (2000%8==0): swz=(bid%8)*250+bid/8. XCD x owns
//     b in {2x,2x+1} and walks their chunks sequentially => 16 compact
//     linear streams at DRAM; warmup rows are own-XCD L2 hits.
// Everything else identical to R6 (L=16, W=8, phase-separated stores,
// sched_barriers, __launch_bounds__(256,4)).

constexpr int B_ = 16;
constexpr int T_ = 4000;
constexpr int C_ = 512;
constexpr int L_ = 16;            // output timesteps per thread
constexpr int W_ = 8;             // lookback warmup (0.1^8 ~ 1e-8)
constexpr int NC4_ = C_ / 4;      // 128 float4 columns per row
constexpr int NCHUNK_ = T_ / L_;  // 250
constexpr int NXCD_ = 8;
constexpr int NWG_ = B_ * NC4_ * NCHUNK_ / 256;  // 2000
constexpr int CPX_ = NWG_ / NXCD_;               // 250 blocks per XCD

__global__ __launch_bounds__(256, 4) void ema_chunk_scan(const float* __restrict__ x,
                                                         float* __restrict__ y) {
    // Bijective XCD-chunked block swizzle (NWG_ % NXCD_ == 0).
    int swz = (blockIdx.x % NXCD_) * CPX_ + blockIdx.x / NXCD_;

    // chunk-major decode: swz in [0,2000). b = swz/125 (each b spans 125
    // blocks = 250 chunks); block covers chunk pair (swz%125)*2 + half.
    int half = threadIdx.x >> 7;          // 0 or 1 (two chunks per block)
    int c4   = threadIdx.x & (NC4_ - 1);  // lane-major -> coalesced
    int b     = swz / 125;                // wave-uniform
    int chunk = (swz % 125) * 2 + half;   // wave-uniform

    int t0 = chunk * L_;
    int tw = (chunk > 0) ? (t0 - W_) : 0;

    const float4* base = (const float4*)(x + (size_t)b * T_ * C_) + c4;
    float4*       q    = (float4*)(y + ((size_t)b * T_ + t0) * C_) + c4;

    // ---- phase 1: issue ALL 24 loads ----
    float4 w[W_];
    #pragma unroll
    for (int i = 0; i < W_; ++i) w[i] = base[(size_t)(tw + i) * NC4_];
    float4 m[L_];
    #pragma unroll
    for (int i = 0; i < L_; ++i) m[i] = base[(size_t)(t0 + i) * NC4_];
    __builtin_amdgcn_sched_barrier(0);

    const float a = 0.9f, om = 0.1f;
    float4 acc = make_float4(0.f, 0.f, 0.f, 0.f);

    // ---- phase 2: warmup chain (no stores) ----
    #pragma unroll
    for (int i = 0; i < W_; ++i) {
        acc.x = om * acc.x + a * w[i].x;
        acc.y = om * acc.y + a * w[i].y;
        acc.z = om * acc.z + a * w[i].z;
        acc.w = om * acc.w + a * w[i].w;
    }
    // chunk 0: no history — zero the warmup state (wave-uniform select).
    float sel = (chunk > 0) ? 1.f : 0.f;
    acc.x *= sel; acc.y *= sel; acc.z *= sel; acc.w *= sel;

    // main chain into registers (no stores yet)
    float4 o[L_];
    #pragma unroll
    for (int i = 0; i < L_; ++i) {
        acc.x = om * acc.x + a * m[i].x;
        acc.y = om * acc.y + a * m[i].y;
        acc.z = om * acc.z + a * m[i].z;
        acc.w = om * acc.w + a * m[i].w;
        o[i] = acc;
    }
    __builtin_amdgcn_sched_barrier(0);

    // ---- phase 3: pure store burst ----
    #pragma unroll
    for (int i = 0; i < L_; ++i) {
        q[(size_t)i * NC4_] = o[i];
    }
}

extern "C" void kernel_launch(void* const* d_in, const int* in_sizes, int n_in,
                              void* d_out, int out_size, void* d_ws, size_t ws_size,
                              hipStream_t stream) {
    const float* x = (const float*)d_in[0];
    float* y = (float*)d_out;
    ema_chunk_scan<<<NWG_, 256, 0, stream>>>(x, y);
}